// Round 6
// baseline (698.857 us; speedup 1.0000x reference)
//
#include <hip/hip_runtime.h>
#include <math.h>

#define B    32
#define S    2048
#define D    512
#define H    512
#define G4   2048
#define NP   8
#define KC   16      // k-chunks of 64 over concat-K 1024 (kc<8: W_ih/xin, kc>=8: W_hh/h)
#define NCH  8       // S / SCHUNK
#define SCHUNK 256
#define NBLK 256     // == #CUs; 1 block/CU co-residency
#define NTHR 512
#define NBAR 31      // 4 barriers/step * 8 steps - 1 (skip last)

__device__ __forceinline__ float sigmoidf_(float x) {
  return 1.0f / (1.0f + __expf(-x));
}

// Grid barrier without cooperative launch. Per-barrier dedicated counters
// (zeroed by k_init each call). Arrival: agent-scope RELEASE fetch_add
// (writes back dirty L2 -> coherence point; proven cross-XCD in round 3).
// Spin: RELAXED polls (sc1, served at coherence point; no cache-inv per poll
// -- round 3's mistake). Exit: one ACQUIRE fence (invalidates L1/L2 once).
// 8 slots spread 64B apart reduce same-line atomic serialization.
__device__ __forceinline__ void gbar(int* cnt, int bi) {
  __syncthreads();
  if (threadIdx.x == 0) {
    int* base = cnt + bi * 128;
    __hip_atomic_fetch_add(base + (blockIdx.x & 7) * 16, 1,
                           __ATOMIC_RELEASE, __HIP_MEMORY_SCOPE_AGENT);
    int s;
    do {
      s = 0;
      #pragma unroll
      for (int q = 0; q < 8; ++q)
        s += __hip_atomic_load(base + q * 16, __ATOMIC_RELAXED, __HIP_MEMORY_SCOPE_AGENT);
      if (s < NBLK) __builtin_amdgcn_s_sleep(1);
    } while (s < NBLK);
    __builtin_amdgcn_fence(__ATOMIC_ACQUIRE, "agent");
  }
  __syncthreads();
}

// init: transpose Wcat -> Wt[k][j] (LDS-tiled), broadcast states, zero barrier
// counters (fresh each call -> replay-safe), normalize num_sent dtype.
__global__ __launch_bounds__(256)
void k_init(const float* __restrict__ W_ih, const float* __restrict__ W_hh,
            const float* __restrict__ init_h, const float* __restrict__ init_c,
            const float* __restrict__ init_in, const int* __restrict__ ns_raw,
            float* __restrict__ Wt, float* __restrict__ h, float* __restrict__ c,
            float* __restrict__ x, int* __restrict__ ns, int* __restrict__ cnt) {
  __shared__ float tbuf[64][65];
  const int blk = blockIdx.x, tid = threadIdx.x;
  // transpose tile (32 jt x 16 kt of 64x64)
  const int jt = blk & 31, kt = blk >> 5;
  const int j0 = jt * 64, k0 = kt * 64;
  const int r0 = tid >> 6, cc = tid & 63;
  for (int rr = r0; rr < 64; rr += 4) {
    int j = j0 + rr, k = k0 + cc;
    tbuf[rr][cc] = (k < 512) ? W_ih[(size_t)j * 512 + k]
                             : W_hh[(size_t)j * 512 + (k - 512)];
  }
  __syncthreads();
  for (int rr = r0; rr < 64; rr += 4)
    Wt[(size_t)(k0 + rr) * 2048 + j0 + cc] = tbuf[cc][rr];

  int idx = blk * 256 + tid;
  if (idx < B * H) {
    int d = idx & 511;
    h[idx] = init_h[d]; c[idx] = init_c[d]; x[idx] = init_in[d];
  }
  if (idx < NBAR * 128) cnt[idx] = 0;
  if (idx == 0) {
    // num_sent >= 1 always. If int64 (LE), high word of elem 0 (raw[1]) is 0.
    bool is64 = (ns_raw[1] == 0);
    for (int i = 0; i < B; ++i) ns[i] = is64 ? ns_raw[2 * i] : ns_raw[i];
  }
}

// One persistent (non-cooperative) kernel, 256 blocks x 512 threads.
// Per step: gates | bar | hc+q | bar | attn | bar | reduce+score | bar
__global__ __launch_bounds__(NTHR, 2)
void k_persist(const float* __restrict__ enc,
               const float* __restrict__ b_ih, const float* __restrict__ b_hh,
               const float* __restrict__ Wq, const float* __restrict__ score_W,
               const float* __restrict__ score_b, const float* __restrict__ Wt,
               float* __restrict__ out, float* __restrict__ xin,
               float* __restrict__ hbuf, float* __restrict__ cbuf,
               float* __restrict__ qbuf, float* __restrict__ part,
               float* __restrict__ ch_m, float* __restrict__ ch_l,
               float* __restrict__ ch_o, const int* __restrict__ ns,
               int* __restrict__ cnt) {
  __shared__ float hs[512];
  __shared__ float qp_[8][64];
  __shared__ float wm[8], wl[8];
  __shared__ float wo[8][512];
  __shared__ float red[512];

  const int blk = blockIdx.x;
  const int tid = threadIdx.x;

  for (int t = 0; t < NP; ++t) {
    // ---- phase 1: gates split-K, register/SGPR form (no LDS) ----
    // blk = jt(4)*64 + bt(4)*16 + kc(16). One j per thread (coalesced Wt reads);
    // X values wave-uniform -> s_loads; 8 FMA per w-load.
    {
      const int jt = blk >> 6;
      const int bt = (blk >> 4) & 3;
      const int kc = blk & 15;
      const int j  = jt * 512 + tid;
      const int b0 = bt * 8;
      const int k0c = kc * 64;
      const float* Xb = ((kc < 8) ? xin : hbuf) + (k0c & 511);
      const float* wp = Wt + (size_t)k0c * 2048 + j;
      float acc[8] = {0,0,0,0,0,0,0,0};
      #pragma unroll 4
      for (int k = 0; k < 64; ++k) {
        float wv = wp[(size_t)k * 2048];
        #pragma unroll
        for (int bi = 0; bi < 8; ++bi)
          acc[bi] += wv * Xb[(b0 + bi) * 512 + k];
      }
      #pragma unroll
      for (int bi = 0; bi < 8; ++bi)
        part[((size_t)kc * B + b0 + bi) * G4 + j] = acc[bi];
    }
    gbar(cnt, t * 4 + 0);

    // ---- phase 2: hc + q. blk = b(32) x dc(8); each block redundantly
    // computes h[b] (cheap), dc==0 persists h,c; block computes q slice dc.
    // c double-buffered (read t&1, write (t+1)&1) to avoid same-phase WAR.
    {
      const int b  = blk >> 3;
      const int dc = blk & 7;
      const float* cr = cbuf + (t & 1) * (B * H);
      float*       cw = cbuf + ((t + 1) & 1) * (B * H);
      const int idx = b * 512 + tid;
      float g[4];
      #pragma unroll
      for (int gi = 0; gi < 4; ++gi) {
        const int jj = gi * 512 + tid;
        float sg = b_ih[jj] + b_hh[jj];
        #pragma unroll
        for (int kcc = 0; kcc < KC; ++kcc)
          sg += part[((size_t)kcc * B + b) * G4 + jj];
        g[gi] = sg;
      }
      float i_ = sigmoidf_(g[0]), f_ = sigmoidf_(g[1]);
      float gg = tanhf(g[2]),     o_ = sigmoidf_(g[3]);
      float cn = f_ * cr[idx] + i_ * gg;
      float hv = o_ * tanhf(cn);
      if (dc == 0) { cw[idx] = cn; hbuf[idx] = hv; }
      hs[tid] = hv;
      __syncthreads();
      const int dl = tid & 63, kg = tid >> 6;
      const int d  = dc * 64 + dl;
      float p = 0.f;
      #pragma unroll 8
      for (int k = kg * 64; k < kg * 64 + 64; ++k)
        p += hs[k] * Wq[(size_t)k * 512 + d];
      qp_[kg][dl] = p;
      __syncthreads();
      if (tid < 64) {
        float sq = 0.f;
        #pragma unroll
        for (int q = 0; q < 8; ++q) sq += qp_[q][tid];
        qbuf[b * 512 + dc * 64 + tid] = sq;
      }
    }
    gbar(cnt, t * 4 + 1);

    // ---- phase 3: attn. blk = b(32) x ch(8); 8 waves, pairwise rows,
    // 1-pair-deep prefetch (round-4 proven loop) ----
    {
      const int b  = blk >> 3;
      const int ch = blk & 7;
      const int s0 = ch * SCHUNK;
      const int nsb = ns[b];
      const int lane = tid & 63;
      const int wv = tid >> 6;   // 0..7

      const float4* qv = (const float4*)(qbuf + b * 512 + lane * 8);
      const float4 qa = qv[0], qb4 = qv[1];

      float m = -1e30f, l = 0.f;
      float o0=0,o1=0,o2=0,o3=0,o4=0,o5=0,o6=0,o7=0;

      const int send = min(s0 + SCHUNK, nsb);
      const size_t rowbase = (size_t)b * S;

      int r = s0 + 2 * wv;
      if (r < send) {
        bool has1 = (r + 1 < send);
        const float4* p0 = (const float4*)(enc + (rowbase + r) * 512 + lane * 8);
        const float4* p1 = (const float4*)(enc + (rowbase + (has1 ? r + 1 : r)) * 512 + lane * 8);
        float4 a0 = p0[0], a1 = p0[1];
        float4 c0 = p1[0], c1 = p1[1];
        while (true) {
          const int rn = r + 16;
          const bool hasn = (rn < send);
          float4 na0, na1, nc0, nc1;
          bool nhas1 = false;
          if (hasn) {
            nhas1 = (rn + 1 < send);
            const float4* f0 = (const float4*)(enc + (rowbase + rn) * 512 + lane * 8);
            const float4* f1 = (const float4*)(enc + (rowbase + (nhas1 ? rn + 1 : rn)) * 512 + lane * 8);
            na0 = f0[0]; na1 = f0[1]; nc0 = f1[0]; nc1 = f1[1];
          }
          float d0 = qa.x*a0.x + qa.y*a0.y + qa.z*a0.z + qa.w*a0.w
                   + qb4.x*a1.x + qb4.y*a1.y + qb4.z*a1.z + qb4.w*a1.w;
          float d1 = qa.x*c0.x + qa.y*c0.y + qa.z*c0.z + qa.w*c0.w
                   + qb4.x*c1.x + qb4.y*c1.y + qb4.z*c1.z + qb4.w*c1.w;
          #pragma unroll
          for (int off = 32; off > 0; off >>= 1) {
            d0 += __shfl_xor(d0, off);
            d1 += __shfl_xor(d1, off);
          }
          if (!has1) d1 = -1e30f;          // wave-uniform
          float nm = fmaxf(m, fmaxf(d0, d1));
          float sc = __expf(m - nm);
          float w0 = __expf(d0 - nm);
          float w1 = __expf(d1 - nm);      // 0 when pair's 2nd row invalid
          l = l * sc + w0 + w1;
          o0 = o0*sc + w0*a0.x + w1*c0.x; o1 = o1*sc + w0*a0.y + w1*c0.y;
          o2 = o2*sc + w0*a0.z + w1*c0.z; o3 = o3*sc + w0*a0.w + w1*c0.w;
          o4 = o4*sc + w0*a1.x + w1*c1.x; o5 = o5*sc + w0*a1.y + w1*c1.y;
          o6 = o6*sc + w0*a1.z + w1*c1.z; o7 = o7*sc + w0*a1.w + w1*c1.w;
          m = nm;
          if (!hasn) break;
          r = rn; has1 = nhas1;
          a0 = na0; a1 = na1; c0 = nc0; c1 = nc1;
        }
      }
      if (lane == 0) { wm[wv] = m; wl[wv] = l; }
      float4* wop = (float4*)&wo[wv][lane * 8];
      wop[0] = make_float4(o0, o1, o2, o3);
      wop[1] = make_float4(o4, o5, o6, o7);
      __syncthreads();

      float M = wm[0];
      #pragma unroll
      for (int w = 1; w < 8; ++w) M = fmaxf(M, wm[w]);
      float e[8]; float L = 0.f;
      #pragma unroll
      for (int w = 0; w < 8; ++w) { e[w] = __expf(wm[w] - M); L += wl[w] * e[w]; }
      if (tid == 0) { ch_m[b * NCH + ch] = M; ch_l[b * NCH + ch] = L; }
      float v = 0.f;
      #pragma unroll
      for (int w = 0; w < 8; ++w) v += wo[w][tid] * e[w];
      ch_o[((size_t)(b * NCH + ch)) * 512 + tid] = v;
    }
    gbar(cnt, t * 4 + 2);

    // ---- phase 4: reduce + score (blocks 0..31) ----
    if (blk < B) {
      const int b = blk;
      float M = -1e30f;
      #pragma unroll
      for (int c = 0; c < NCH; ++c) M = fmaxf(M, ch_m[b * NCH + c]);
      float e[NCH]; float L = 0.f;
      #pragma unroll
      for (int c = 0; c < NCH; ++c) {
        e[c] = __expf(ch_m[b * NCH + c] - M);
        L += ch_l[b * NCH + c] * e[c];
      }
      const float invL = 1.0f / L;
      float v = 0.f;
      #pragma unroll
      for (int c = 0; c < NCH; ++c)
        v += ch_o[((size_t)(b * NCH + c)) * 512 + tid] * e[c];
      v *= invL;
      xin[b * 512 + tid] = v;
      red[tid] = v * score_W[tid];
      __syncthreads();
      for (int st = 256; st > 0; st >>= 1) {
        if (tid < st) red[tid] += red[tid + st];
        __syncthreads();
      }
      if (tid == 0) out[t * B + b] = red[0] + score_b[0];
    }
    if (t < NP - 1) gbar(cnt, t * 4 + 3);
  }
}

extern "C" void kernel_launch(void* const* d_in, const int* in_sizes, int n_in,
                              void* d_out, int out_size, void* d_ws, size_t ws_size,
                              hipStream_t stream) {
  const float* enc     = (const float*)d_in[0];
  const int*   ns_raw  = (const int*)d_in[1];
  // d_in[2] = num_pred (8)
  const float* init_h  = (const float*)d_in[3];
  const float* init_c  = (const float*)d_in[4];
  const float* init_in = (const float*)d_in[5];
  const float* W_ih    = (const float*)d_in[6];
  const float* W_hh    = (const float*)d_in[7];
  const float* b_ih    = (const float*)d_in[8];
  const float* b_hh    = (const float*)d_in[9];
  const float* Wq      = (const float*)d_in[10];
  const float* score_W = (const float*)d_in[11];
  const float* score_b = (const float*)d_in[12];
  float* out = (float*)d_out;

  float* ws    = (float*)d_ws;
  float* xin   = ws;                 // 16384
  float* hbuf  = ws + 16384;         // 16384
  float* cbuf  = ws + 32768;         // 32768 (double-buffered)
  float* qbuf  = ws + 65536;         // 16384
  float* part  = ws + 81920;         // KC*B*G4 = 1048576
  float* ch_m  = ws + 1130496;       // 256
  float* ch_l  = ws + 1130752;       // 256
  float* ch_o  = ws + 1131008;       // B*NCH*D = 131072
  float* Wt    = ws + 1262080;       // 1024*2048 = 2097152
  int*   ns    = (int*)(ws + 3359232);   // 32 ints
  int*   cnt   = (int*)(ws + 3359264);   // NBAR*128 = 3968 ints (64B-strided slots)

  k_init<<<512, 256, 0, stream>>>(W_ih, W_hh, init_h, init_c, init_in, ns_raw,
                                  Wt, hbuf, cbuf, xin, ns, cnt);
  k_persist<<<NBLK, NTHR, 0, stream>>>(enc, b_ih, b_hh, Wq, score_W, score_b, Wt,
                                       out, xin, hbuf, cbuf, qbuf, part,
                                       ch_m, ch_l, ch_o, ns, cnt);
}

// Round 7
// 354.091 us; speedup vs baseline: 1.9737x; 1.9737x over previous
//
#include <hip/hip_runtime.h>
#include <math.h>

#define B    32
#define S    2048
#define D    512
#define H    512
#define NP   8
#define NSL  32     // hid-slices per step kernel
#define HSL  16     // hid per slice
#define NBT  4      // batch groups
#define BG   8      // batches per group
#define NCH  8      // attn chunks
#define SCHUNK 256

__device__ __forceinline__ float sigmoidf_(float x) {
  return 1.0f / (1.0f + __expf(-x));
}

// ---------------- init: Wt = [W_ih | W_hh]^T (Wt[k][j]), states, num_sent ----------------
__global__ __launch_bounds__(256)
void k_init(const float* __restrict__ W_ih, const float* __restrict__ W_hh,
            const float* __restrict__ init_h, const float* __restrict__ init_c,
            const float* __restrict__ init_in, const int* __restrict__ ns_raw,
            float* __restrict__ Wt, float* __restrict__ hbuf, float* __restrict__ cbuf,
            float* __restrict__ xin0, int* __restrict__ ns) {
  __shared__ float tbuf[64][65];
  const int blk = blockIdx.x, tid = threadIdx.x;
  const int jt = blk & 31, kt = blk >> 5;        // 32 j-tiles x 16 k-tiles of 64x64
  const int j0 = jt * 64, k0 = kt * 64;
  const int r0 = tid >> 6, cc = tid & 63;
  for (int rr = r0; rr < 64; rr += 4) {
    int j = j0 + rr, k = k0 + cc;
    tbuf[rr][cc] = (k < 512) ? W_ih[(size_t)j * 512 + k]
                             : W_hh[(size_t)j * 512 + (k - 512)];
  }
  __syncthreads();
  for (int rr = r0; rr < 64; rr += 4)
    Wt[(size_t)(k0 + rr) * 2048 + j0 + cc] = tbuf[cc][rr];

  int idx = blk * 256 + tid;
  if (idx < B * H) {
    int d = idx & 511;
    hbuf[idx] = init_h[d];   // buffer 0
    cbuf[idx] = init_c[d];
    xin0[idx] = init_in[d];
  }
  if (idx == 0) {
    // num_sent >= 1 always. If int64 (LE), high word of elem 0 (raw[1]) is 0.
    bool is64 = (ns_raw[1] == 0);
    for (int i = 0; i < B; ++i) ns[i] = is64 ? ns_raw[2 * i] : ns_raw[i];
  }
}

// ---------------- fused step kernel ----------------
// grid 128 = (sl: 32 hid-slices) x (bg: 4 groups of 8 batches), 512 threads.
// Phase A: reduce(t-1): combine attn chunk partials -> xin (LDS only) + score -> out[t-1]
// Phase B: gates for rows {gi*512 + sl*16 + ho} x 8 batches, full K=1024 (Wt coalesced,
//          X from LDS broadcast reads), kc-split over 8 waves, LDS reduce
// Phase C: LSTM cell -> h(t) (double-buffered), c; q-partials qpart[sl][b][d]
// t==8: phase A only (final score).
__global__ __launch_bounds__(512, 1)
void k_step(const float* __restrict__ xin0, const float* __restrict__ bih,
            const float* __restrict__ bhh, const float* __restrict__ Wq,
            const float* __restrict__ scW, const float* __restrict__ scb,
            const float* __restrict__ Wt,
            const float* __restrict__ ch_m, const float* __restrict__ ch_l,
            const float* __restrict__ ch_o,
            float* __restrict__ hbuf, float* __restrict__ cbuf,
            float* __restrict__ qpart, float* __restrict__ out, int t) {
  __shared__ float X[BG][1024];       // 32 KB: [xin | h(t-1)] per batch
  __shared__ float gacc[8][64][9];    // 18 KB (pad 9 -> 2-way banks)
  __shared__ float gl[4][16][8];      // gate values
  __shared__ float hl[8][16];         // h slice for qpart
  __shared__ float sred[8][8];        // score partials [wave][b]

  const int tid = threadIdx.x;
  const int sl = blockIdx.x >> 2;     // 0..31
  const int bg = blockIdx.x & 3;      // 0..3
  const int b0 = bg * BG;

  // ---- phase A ----
  if (t == 0) {
    #pragma unroll
    for (int bl = 0; bl < BG; ++bl)
      X[bl][tid] = xin0[(b0 + bl) * 512 + tid];
  } else {
    const float swd = scW[tid];
    #pragma unroll
    for (int bl = 0; bl < BG; ++bl) {
      const int b = b0 + bl;
      float M = -1e30f;
      #pragma unroll
      for (int c = 0; c < NCH; ++c) M = fmaxf(M, ch_m[b * NCH + c]);
      float e[NCH]; float L = 0.f;
      #pragma unroll
      for (int c = 0; c < NCH; ++c) {
        e[c] = __expf(ch_m[b * NCH + c] - M);
        L += ch_l[b * NCH + c] * e[c];
      }
      float v = 0.f;
      #pragma unroll
      for (int c = 0; c < NCH; ++c)
        v += ch_o[((size_t)(b * NCH + c)) * 512 + tid] * e[c];
      v *= (1.0f / L);
      X[bl][tid] = v;
      float p = v * swd;
      #pragma unroll
      for (int off = 32; off > 0; off >>= 1) p += __shfl_xor(p, off);
      if ((tid & 63) == 0) sred[tid >> 6][bl] = p;
    }
  }
  // copy h(t-1) into X[.][512..1023]
  if (t < NP) {
    const float4* hsrc = (const float4*)(hbuf + (t & 1) * (B * 512));
    #pragma unroll
    for (int it = 0; it < 2; ++it) {
      int idx = it * 512 + tid;      // 0..1023
      int bl = idx >> 7;
      int off = idx & 127;
      float4 hv = hsrc[(b0 + bl) * 128 + off];
      *(float4*)&X[bl][512 + off * 4] = hv;
    }
  }
  __syncthreads();

  if (t >= 1 && tid < BG) {
    float s = 0.f;
    #pragma unroll
    for (int w = 0; w < 8; ++w) s += sred[w][tid];
    if (sl == 0) out[(t - 1) * B + b0 + tid] = s + scb[0];
  }
  if (t >= NP) return;   // t==8: final-score-only call

  // ---- phase B: gates ----
  {
    const int jloc = tid & 63;              // (gi, ho)
    const int kc = tid >> 6;                // wave id = k-chunk
    const int gi = jloc >> 4, ho = jloc & 15;
    const int jg = gi * 512 + sl * HSL + ho;
    const int k0c = kc * 128;
    const float* wp = Wt + (size_t)k0c * 2048 + jg;
    float acc[BG] = {0, 0, 0, 0, 0, 0, 0, 0};
    for (int kk = 0; kk < 32; ++kk) {
      float wv0 = wp[(size_t)(kk * 4 + 0) * 2048];
      float wv1 = wp[(size_t)(kk * 4 + 1) * 2048];
      float wv2 = wp[(size_t)(kk * 4 + 2) * 2048];
      float wv3 = wp[(size_t)(kk * 4 + 3) * 2048];
      #pragma unroll
      for (int bl = 0; bl < BG; ++bl) {
        const float4 xv = *(const float4*)&X[bl][k0c + kk * 4];  // LDS broadcast
        acc[bl] += wv0 * xv.x + wv1 * xv.y + wv2 * xv.z + wv3 * xv.w;
      }
    }
    #pragma unroll
    for (int bl = 0; bl < BG; ++bl) gacc[kc][jloc][bl] = acc[bl];
  }
  __syncthreads();

  // ---- kc-reduce + bias -> gl ----
  {
    const int bl = tid >> 6, jloc = tid & 63;
    const int gi = jloc >> 4, ho = jloc & 15;
    const int jg = gi * 512 + sl * HSL + ho;
    float g = bih[jg] + bhh[jg];
    #pragma unroll
    for (int kc = 0; kc < 8; ++kc) g += gacc[kc][jloc][bl];
    gl[gi][ho][bl] = g;
  }
  __syncthreads();

  // ---- LSTM cell ----
  if (tid < 128) {
    const int ho = tid & 15, bl = tid >> 4;
    const int bglob = b0 + bl, hid = sl * HSL + ho;
    float i_ = sigmoidf_(gl[0][ho][bl]);
    float f_ = sigmoidf_(gl[1][ho][bl]);
    float g_ = tanhf(gl[2][ho][bl]);
    float o_ = sigmoidf_(gl[3][ho][bl]);
    float cv = cbuf[bglob * 512 + hid];          // unique owner (sl,bg)
    float cn = f_ * cv + i_ * g_;
    cbuf[bglob * 512 + hid] = cn;
    float hv = o_ * tanhf(cn);
    hbuf[((t + 1) & 1) * (B * 512) + bglob * 512 + hid] = hv;
    hl[bl][ho] = hv;
  }
  __syncthreads();

  // ---- q-partials: qpart[sl][b][d] = sum_{ho} h[b][sl*16+ho] * Wq[sl*16+ho][d] ----
  {
    float w[HSL];
    #pragma unroll
    for (int ho = 0; ho < HSL; ++ho)
      w[ho] = Wq[(size_t)(sl * HSL + ho) * 512 + tid];
    #pragma unroll
    for (int bl = 0; bl < BG; ++bl) {
      float acc = 0.f;
      #pragma unroll
      for (int ho = 0; ho < HSL; ++ho) acc += hl[bl][ho] * w[ho];
      qpart[((size_t)sl * B + b0 + bl) * 512 + tid] = acc;
    }
  }
}

// ---------------- attn: q = sum(qpart), then one-pass online softmax over chunk ----------------
// grid 256 = (b: 32) x (ch: 8), 512 threads = 8 waves; pairwise rows + 1-pair prefetch.
__global__ __launch_bounds__(512, 1)
void k_attn(const float* __restrict__ enc, const float* __restrict__ qpart,
            const int* __restrict__ ns_buf, float* __restrict__ ch_m,
            float* __restrict__ ch_l, float* __restrict__ ch_o) {
  __shared__ float q_lds[512];
  __shared__ float wm[8], wl[8];
  __shared__ float wo[8][512];
  const int b  = blockIdx.x >> 3;
  const int ch = blockIdx.x & 7;
  const int tid = threadIdx.x;
  const int lane = tid & 63;
  const int wv = tid >> 6;

  // q = sum over 32 slices
  {
    float s = 0.f;
    #pragma unroll
    for (int sl = 0; sl < NSL; ++sl)
      s += qpart[((size_t)sl * B + b) * 512 + tid];
    q_lds[tid] = s;
  }
  __syncthreads();

  const float4 qa  = *(const float4*)&q_lds[lane * 8];
  const float4 qb4 = *(const float4*)&q_lds[lane * 8 + 4];

  const int s0 = ch * SCHUNK;
  const int nsb = ns_buf[b];
  float m = -1e30f, l = 0.f;
  float o0=0,o1=0,o2=0,o3=0,o4=0,o5=0,o6=0,o7=0;

  const int send = min(s0 + SCHUNK, nsb);
  const size_t rowbase = (size_t)b * S;

  int r = s0 + 2 * wv;
  if (r < send) {
    bool has1 = (r + 1 < send);
    const float4* p0 = (const float4*)(enc + (rowbase + r) * 512 + lane * 8);
    const float4* p1 = (const float4*)(enc + (rowbase + (has1 ? r + 1 : r)) * 512 + lane * 8);
    float4 a0 = p0[0], a1 = p0[1];
    float4 c0 = p1[0], c1 = p1[1];
    while (true) {
      const int rn = r + 16;
      const bool hasn = (rn < send);
      float4 na0, na1, nc0, nc1;
      bool nhas1 = false;
      if (hasn) {
        nhas1 = (rn + 1 < send);
        const float4* f0 = (const float4*)(enc + (rowbase + rn) * 512 + lane * 8);
        const float4* f1 = (const float4*)(enc + (rowbase + (nhas1 ? rn + 1 : rn)) * 512 + lane * 8);
        na0 = f0[0]; na1 = f0[1]; nc0 = f1[0]; nc1 = f1[1];
      }
      float d0 = qa.x*a0.x + qa.y*a0.y + qa.z*a0.z + qa.w*a0.w
               + qb4.x*a1.x + qb4.y*a1.y + qb4.z*a1.z + qb4.w*a1.w;
      float d1 = qa.x*c0.x + qa.y*c0.y + qa.z*c0.z + qa.w*c0.w
               + qb4.x*c1.x + qb4.y*c1.y + qb4.z*c1.z + qb4.w*c1.w;
      #pragma unroll
      for (int off = 32; off > 0; off >>= 1) {
        d0 += __shfl_xor(d0, off);
        d1 += __shfl_xor(d1, off);
      }
      if (!has1) d1 = -1e30f;            // wave-uniform
      float nm = fmaxf(m, fmaxf(d0, d1));
      float sc = __expf(m - nm);
      float w0 = __expf(d0 - nm);
      float w1 = __expf(d1 - nm);        // 0 when pair's 2nd row invalid
      l = l * sc + w0 + w1;
      o0 = o0*sc + w0*a0.x + w1*c0.x; o1 = o1*sc + w0*a0.y + w1*c0.y;
      o2 = o2*sc + w0*a0.z + w1*c0.z; o3 = o3*sc + w0*a0.w + w1*c0.w;
      o4 = o4*sc + w0*a1.x + w1*c1.x; o5 = o5*sc + w0*a1.y + w1*c1.y;
      o6 = o6*sc + w0*a1.z + w1*c1.z; o7 = o7*sc + w0*a1.w + w1*c1.w;
      m = nm;
      if (!hasn) break;
      r = rn; has1 = nhas1;
      a0 = na0; a1 = na1; c0 = nc0; c1 = nc1;
    }
  }
  if (lane == 0) { wm[wv] = m; wl[wv] = l; }
  float4* wop = (float4*)&wo[wv][lane * 8];
  wop[0] = make_float4(o0, o1, o2, o3);
  wop[1] = make_float4(o4, o5, o6, o7);
  __syncthreads();

  float M = wm[0];
  #pragma unroll
  for (int w = 1; w < 8; ++w) M = fmaxf(M, wm[w]);
  float e[8]; float L = 0.f;
  #pragma unroll
  for (int w = 0; w < 8; ++w) { e[w] = __expf(wm[w] - M); L += wl[w] * e[w]; }
  if (tid == 0) { ch_m[b * NCH + ch] = M; ch_l[b * NCH + ch] = L; }
  float v = 0.f;
  #pragma unroll
  for (int w = 0; w < 8; ++w) v += wo[w][tid] * e[w];
  ch_o[((size_t)(b * NCH + ch)) * 512 + tid] = v;
}

extern "C" void kernel_launch(void* const* d_in, const int* in_sizes, int n_in,
                              void* d_out, int out_size, void* d_ws, size_t ws_size,
                              hipStream_t stream) {
  const float* enc     = (const float*)d_in[0];
  const int*   ns_raw  = (const int*)d_in[1];
  // d_in[2] = num_pred (8)
  const float* init_h  = (const float*)d_in[3];
  const float* init_c  = (const float*)d_in[4];
  const float* init_in = (const float*)d_in[5];
  const float* W_ih    = (const float*)d_in[6];
  const float* W_hh    = (const float*)d_in[7];
  const float* b_ih    = (const float*)d_in[8];
  const float* b_hh    = (const float*)d_in[9];
  const float* Wq      = (const float*)d_in[10];
  const float* score_W = (const float*)d_in[11];
  const float* score_b = (const float*)d_in[12];
  float* out = (float*)d_out;

  float* ws    = (float*)d_ws;
  float* Wt    = ws;                  // 1024*2048 = 2097152
  float* hbuf  = ws + 2097152;        // 2*B*H = 32768 (double-buffered)
  float* cbuf  = ws + 2129920;        // 16384
  float* xin0  = ws + 2146304;        // 16384
  float* qpart = ws + 2162688;        // NSL*B*512 = 524288
  float* ch_m  = ws + 2686976;        // 256
  float* ch_l  = ws + 2687232;        // 256
  float* ch_o  = ws + 2687488;        // B*NCH*512 = 131072
  int*   ns    = (int*)(ws + 2818560);  // 32 ints

  k_init<<<512, 256, 0, stream>>>(W_ih, W_hh, init_h, init_c, init_in, ns_raw,
                                  Wt, hbuf, cbuf, xin0, ns);
  for (int t = 0; t < NP; ++t) {
    k_step<<<NSL * NBT, 512, 0, stream>>>(xin0, b_ih, b_hh, Wq, score_W, score_b, Wt,
                                          ch_m, ch_l, ch_o, hbuf, cbuf, qpart, out, t);
    k_attn<<<B * NCH, 512, 0, stream>>>(enc, qpart, ns, ch_m, ch_l, ch_o);
  }
  k_step<<<NSL * NBT, 512, 0, stream>>>(xin0, b_ih, b_hh, Wq, score_W, score_b, Wt,
                                        ch_m, ch_l, ch_o, hbuf, cbuf, qpart, out, NP);
}